// Round 24
// baseline (49.827 us; speedup 1.0000x reference)
//
#include <hip/hip_runtime.h>
#include <math.h>

// Problem constants
#define BB    16                 // batch
#define HH    112                // input H == W
#define IMSZ  (HH*HH)            // 12544 floats per image plane
#define OO    256                // output channels
#define OHW   108                // output H == W
#define PLANE (OHW*OHW)          // 11664 pixels per (b,o) plane
#define MTOTAL (BB*PLANE)        // 186624 output pixels per o
#define MTILE 256                // pixels per subtile (16 M-frags, 1 per wave)
#define KSUB  3                  // consecutive subtiles per block: 729/3 = 243
#define WRECB 144                // weight record bytes: hi[64] | lo[64] | pad[16]
#define WRECW 36                 // record size in u32 words
#define NXCD  8
#define XCOL  (KSUB*MTILE)       // 768 px per xbuf row
#define XSTR  772                // row stride words: 772 % 32 == 4 -> conflict-free

typedef __attribute__((ext_vector_type(8))) short short8;   // 8 bf16 = 4 VGPR
typedef __attribute__((ext_vector_type(4))) float f32x4;

// round-to-nearest-even float -> bf16 (bit trick; inputs finite)
__device__ __forceinline__ unsigned short f2bf(float x) {
    unsigned u = __builtin_bit_cast(unsigned, x);
    return (unsigned short)((u + 0x7fffu + ((u >> 16) & 1u)) >> 16);
}
__device__ __forceinline__ float bf2f(unsigned short h) {
    unsigned u = ((unsigned)h) << 16;
    return __builtin_bit_cast(float, u);
}

// GEMM formulation: xw[p,o] = sum_k win[p][k] * w[o][k], K=25 padded to 32.
// bf16 hi/lo split, 3 MFMAs (hh, hl, lh) per image; d2 = x2 + w2 - 2*xw;
// (sqrt(a)+sqrt(b))^2 = a + b + 2*sqrt(a*b) -> 1 sqrt + 1 exp per output.
// R24: SOLO BLOCK + LDS-TRANSPOSE EPILOGUE (untested combination).
// R15 tested contiguous stores WITH 2-block co-tenancy (neutral); R21 showed
// co-tenant stream interleave is the one confirmed mechanism (-7%). Combo:
// per ot, all waves deposit C into xbuf[16 o][768 px]; wave w then stores
// plane ot*16+w as ~1KB fully-contiguous runs (16x fewer TA segments than
// the 16-plane scattered store). Bank-conflict-free by stride 772 (=4 mod 32).
__global__ __launch_bounds__(1024)
void dist_rbf_mfma(const float* __restrict__ gx, const float* __restrict__ rx,
                   const float* __restrict__ gw, const float* __restrict__ rw,
                   const float* __restrict__ stdp, float* __restrict__ out)
{
    __shared__ __align__(16) unsigned wrec[2 * OO * WRECW];  // 73.7 KB
    __shared__ float w2s[2 * OO];
    __shared__ __align__(16) float xbuf[16 * XSTR];          // 49.4 KB

    const int tid = threadIdx.x;

    // ---- bijective XCD swizzle (m204) on the block index ----
    const int nwg = gridDim.x;                 // 243 (243 % 8 = 3)
    const int hw  = blockIdx.x;
    const int xcd = hw % NXCD, idx = hw / NXCD;
    const int q = nwg / NXCD, r = nwg % NXCD;
    const int lb = (xcd < r ? xcd * (q + 1) : r * (q + 1) + (xcd - r) * q) + idx;

    // ---- stage weights once: threads 0..511: image t>>8, filter t&255 ----
    if (tid < 2 * OO) {
        const int img = tid >> 8;
        const int o   = tid & 255;
        const float* wsrc = img ? rw : gw;
        unsigned* rec = wrec + img * OO * WRECW + o * WRECW;
        float v[32]; unsigned short h[32];
        float s = 0.f;
        #pragma unroll
        for (int i = 0; i < 32; i++) {
            float x = (i < 25) ? wsrc[o * 25 + i] : 0.f;
            v[i] = x; s = fmaf(x, x, s); h[i] = f2bf(x);
        }
        w2s[img * OO + o] = s;
        #pragma unroll
        for (int wd = 0; wd < 16; wd++) {
            rec[wd] = (unsigned)h[2*wd] | ((unsigned)h[2*wd+1] << 16);
            unsigned short l0 = f2bf(v[2*wd]   - bf2f(h[2*wd]));
            unsigned short l1 = f2bf(v[2*wd+1] - bf2f(h[2*wd+1]));
            rec[16 + wd] = (unsigned)l0 | ((unsigned)l1 << 16);
        }
    }
    __syncthreads();

    const int lid  = tid & 63;
    const int wid  = tid >> 6;     // 16 waves; wave owns M-frag `wid`
    const int mcol = lid & 15;     // A: pixel row; B: o col; C: col
    const int kgrp = lid >> 4;     // k-group: k in [kgrp*8, kgrp*8+8)
    const int k0   = kgrp * 8;

    const float sd   = stdp[0];
    const float kneg = -1.f / (2.f * sd * sd);
    const char* wrecB = (const char*)wrec;

    // ---- build A fragments + x2 for all KSUB subtiles (register resident) ----
    short8 ah[KSUB][2], al[KSUB][2];   // [st][img]
    float  x2v[KSUB][2][4];            // [st][img][rr]

    #pragma unroll
    for (int st = 0; st < KSUB; st++) {
        const int pbase = (lb * KSUB + st) * MTILE;   // exact, no tail
        const int p  = pbase + wid * 16 + mcol;       // this lane's A row
        const int b  = p / PLANE;
        const int pp = p - b * PLANE;
        const int oh = pp / OHW;
        const int ow = pp - oh * OHW;
        const size_t ibase = (size_t)b * IMSZ + oh * HH + ow;
        #pragma unroll
        for (int img = 0; img < 2; img++) {
            const float* src = (img == 0 ? gx : rx) + ibase;
            float xs[8];
            float part = 0.f;
            #pragma unroll
            for (int j = 0; j < 8; j++) {
                int k = k0 + j;
                int r2 = k / 5, c2 = k - r2 * 5;
                float x = (k < 25) ? src[r2 * HH + c2] : 0.f;
                xs[j] = x; part = fmaf(x, x, part);
            }
            // reduce partial x2 across the 4 k-groups of this pixel
            part += __shfl_xor(part, 16);
            part += __shfl_xor(part, 32);
            // fetch x2 for the epilogue's C rows (pixels kgrp*4 + rr)
            #pragma unroll
            for (int rr = 0; rr < 4; rr++)
                x2v[st][img][rr] = __shfl(part, kgrp * 4 + rr);
            // bf16 hi/lo split
            short8 hi, lo;
            #pragma unroll
            for (int j = 0; j < 8; j++) {
                unsigned short hh = f2bf(xs[j]);
                hi[j] = (short)hh;
                lo[j] = (short)f2bf(xs[j] - bf2f(hh));
            }
            ah[st][img] = hi; al[st][img] = lo;
        }
    }

    const int pbase768 = lb * XCOL;    // block's 768-px range start

    // ------------- main loop: ot outer; transpose-store epilogue -------------
    for (int ot = 0; ot < 16; ot++) {
        const int o = ot * 16 + mcol;
        const char* recg = wrecB + (size_t)o * WRECB + kgrp * 16;
        const char* recr = recg + (size_t)OO * WRECB;
        short8 bhg = *(const short8*)recg;
        short8 blg = *(const short8*)(recg + 64);
        short8 bhr = *(const short8*)recr;
        short8 blr = *(const short8*)(recr + 64);
        const float w2g = w2s[o];
        const float w2r = w2s[OO + o];

        #pragma unroll
        for (int st = 0; st < KSUB; st++) {
            f32x4 cg = {0.f, 0.f, 0.f, 0.f};
            f32x4 cr = {0.f, 0.f, 0.f, 0.f};
            cg = __builtin_amdgcn_mfma_f32_16x16x32_bf16(ah[st][0], bhg, cg, 0, 0, 0);
            cg = __builtin_amdgcn_mfma_f32_16x16x32_bf16(ah[st][0], blg, cg, 0, 0, 0);
            cg = __builtin_amdgcn_mfma_f32_16x16x32_bf16(al[st][0], bhg, cg, 0, 0, 0);
            cr = __builtin_amdgcn_mfma_f32_16x16x32_bf16(ah[st][1], bhr, cr, 0, 0, 0);
            cr = __builtin_amdgcn_mfma_f32_16x16x32_bf16(ah[st][1], blr, cr, 0, 0, 0);
            cr = __builtin_amdgcn_mfma_f32_16x16x32_bf16(al[st][1], bhr, cr, 0, 0, 0);

            f32x4 res;
            #pragma unroll
            for (int rr = 0; rr < 4; rr++) {
                float d2g = fmaf(-2.f, cg[rr], x2v[st][0][rr] + w2g);
                float d2r = fmaf(-2.f, cr[rr], x2v[st][1][rr] + w2r);
                d2g = fmaxf(d2g, 1e-12f);
                d2r = fmaxf(d2r, 1e-12f);
                // (sqrt(d2g)+sqrt(d2r))^2 = d2g + d2r + 2*sqrt(d2g*d2r)
                float d2 = fmaf(2.f, __builtin_amdgcn_sqrtf(d2g * d2r), d2g + d2r);
                res[rr] = __expf(kneg * d2);
            }
            // deposit transposed: row = o-col (mcol), col = pixel offset
            *(f32x4*)&xbuf[mcol * XSTR + st * MTILE + wid * 16 + kgrp * 4] = res;
        }
        __syncthreads();

        // readback: wave w owns o-row w -> plane ot*16+w; ~1KB contiguous runs
        {
            const int ord = ot * 16 + wid;
            #pragma unroll
            for (int i = 0; i < KSUB; i++) {
                f32x4 v = *(const f32x4*)&xbuf[wid * XSTR + i * MTILE + lid * 4];
                const int p  = pbase768 + i * MTILE + lid * 4;
                const int b  = p / PLANE;
                const int pp = p - b * PLANE;
                *(f32x4*)(out + ((size_t)(b * OO + ord)) * PLANE + pp) = v;
            }
        }
        __syncthreads();   // xbuf WAR protection for next ot
    }
}

extern "C" void kernel_launch(void* const* d_in, const int* in_sizes, int n_in,
                              void* d_out, int out_size, void* d_ws, size_t ws_size,
                              hipStream_t stream) {
    const float* gx   = (const float*)d_in[0];
    const float* rx   = (const float*)d_in[1];
    const float* gw   = (const float*)d_in[2];
    const float* rw   = (const float*)d_in[3];
    const float* stdp = (const float*)d_in[4];
    float* out = (float*)d_out;

    dim3 grid(MTOTAL / (MTILE * KSUB), 1, 1);   // 243 blocks, exact
    dim3 block(1024, 1, 1);
    dist_rbf_mfma<<<grid, block, 0, stream>>>(gx, rx, gw, rw, stdp, out);
}

// Round 25
// 45.899 us; speedup vs baseline: 1.0856x; 1.0856x over previous
//
#include <hip/hip_runtime.h>
#include <math.h>

// Problem constants
#define BB    16                 // batch
#define HH    112                // input H == W
#define IMSZ  (HH*HH)            // 12544 floats per image plane
#define OO    256                // output channels
#define OHW   108                // output H == W
#define PLANE (OHW*OHW)          // 11664 pixels per (b,o) plane
#define MTOTAL (BB*PLANE)        // 186624 output pixels per o
#define MTILE 256                // pixels per subtile (16 M-frags)
#define KSUB  3                  // subtiles per block: 729/3 = 243 blocks
#define WRECB 144                // weight record bytes: hi[64] | lo[64] | pad[16]
#define WRECW 36                 // record size in u32 words
#define NXCD  8

typedef __attribute__((ext_vector_type(8))) short short8;   // 8 bf16 = 4 VGPR
typedef __attribute__((ext_vector_type(4))) float f32x4;

// round-to-nearest-even float -> bf16 (bit trick; inputs finite)
__device__ __forceinline__ unsigned short f2bf(float x) {
    unsigned u = __builtin_bit_cast(unsigned, x);
    return (unsigned short)((u + 0x7fffu + ((u >> 16) & 1u)) >> 16);
}
__device__ __forceinline__ float bf2f(unsigned short h) {
    unsigned u = ((unsigned)h) << 16;
    return __builtin_bit_cast(float, u);
}

// GEMM formulation: xw[p,o] = sum_k win[p][k] * w[o][k], K=25 padded to 32.
// bf16 hi/lo split, 3 MFMAs (hh, hl, lh) per image; d2 = x2 + w2 - 2*xw;
// (sqrt(a)+sqrt(b))^2 = a + b + 2*sqrt(a*b) -> 1 sqrt + 1 exp per output.
// R25: R22 + CONTIGUOUS PER-WAVE FRAGMENTS. R22 gave wave w fragments
// {w, w+16, w+32} (16-px runs 1KB apart; every 128B line split across two
// waves). Now wave w owns fragments {3w, 3w+1, 3w+2} = 48 CONSECUTIVE px:
// per plane per ot the wave issues 3 adjacent dwordx4 (192B run) -> lines
// completed by a single wave, write-combiner-friendly. Same totals/addresses.
__global__ __launch_bounds__(1024)
void dist_rbf_mfma(const float* __restrict__ gx, const float* __restrict__ rx,
                   const float* __restrict__ gw, const float* __restrict__ rw,
                   const float* __restrict__ stdp, float* __restrict__ out)
{
    __shared__ __align__(16) unsigned wrec[2 * OO * WRECW];  // 73.7 KB
    __shared__ float w2s[2 * OO];

    const int tid = threadIdx.x;

    // ---- bijective XCD swizzle (m204) on the block index ----
    const int nwg = gridDim.x;                 // 243 (243 % 8 = 3)
    const int hw  = blockIdx.x;
    const int xcd = hw % NXCD, idx = hw / NXCD;
    const int q = nwg / NXCD, r = nwg % NXCD;
    const int lb = (xcd < r ? xcd * (q + 1) : r * (q + 1) + (xcd - r) * q) + idx;

    // ---- stage weights once: threads 0..511: image t>>8, filter t&255 ----
    if (tid < 2 * OO) {
        const int img = tid >> 8;
        const int o   = tid & 255;
        const float* wsrc = img ? rw : gw;
        unsigned* rec = wrec + img * OO * WRECW + o * WRECW;
        float v[32]; unsigned short h[32];
        float s = 0.f;
        #pragma unroll
        for (int i = 0; i < 32; i++) {
            float x = (i < 25) ? wsrc[o * 25 + i] : 0.f;
            v[i] = x; s = fmaf(x, x, s); h[i] = f2bf(x);
        }
        w2s[img * OO + o] = s;
        #pragma unroll
        for (int wd = 0; wd < 16; wd++) {
            rec[wd] = (unsigned)h[2*wd] | ((unsigned)h[2*wd+1] << 16);
            unsigned short l0 = f2bf(v[2*wd]   - bf2f(h[2*wd]));
            unsigned short l1 = f2bf(v[2*wd+1] - bf2f(h[2*wd+1]));
            rec[16 + wd] = (unsigned)l0 | ((unsigned)l1 << 16);
        }
    }
    __syncthreads();

    const int lid  = tid & 63;
    const int wid  = tid >> 6;     // 16 waves; wave owns px [wid*48, wid*48+48)
    const int mcol = lid & 15;     // A: pixel row; B: o col; C: col
    const int kgrp = lid >> 4;     // k-group: k in [kgrp*8, kgrp*8+8)
    const int k0   = kgrp * 8;

    const float sd   = stdp[0];
    const float kneg = -1.f / (2.f * sd * sd);
    const char* wrecB = (const char*)wrec;
    const int pbase768 = lb * (KSUB * MTILE);  // block's 768-px range start

    // ---- build A fragments + x2 + store bases: wave's 3 ADJACENT frags ----
    short8 ah[KSUB][2], al[KSUB][2];   // [fr][img]
    float  x2v[KSUB][2][4];            // [fr][img][rr]
    float* outbase[KSUB];              // + o*PLANE per ot

    #pragma unroll
    for (int fr = 0; fr < KSUB; fr++) {
        const int prow = pbase768 + wid * 48 + fr * 16;   // frag start px
        const int p  = prow + mcol;                       // this lane's A row
        const int b  = p / PLANE;
        const int pp = p - b * PLANE;
        const int oh = pp / OHW;
        const int ow = pp - oh * OHW;
        const size_t ibase = (size_t)b * IMSZ + oh * HH + ow;
        #pragma unroll
        for (int img = 0; img < 2; img++) {
            const float* src = (img == 0 ? gx : rx) + ibase;
            float xs[8];
            float part = 0.f;
            #pragma unroll
            for (int j = 0; j < 8; j++) {
                int k = k0 + j;
                int r2 = k / 5, c2 = k - r2 * 5;
                float x = (k < 25) ? src[r2 * HH + c2] : 0.f;
                xs[j] = x; part = fmaf(x, x, part);
            }
            // reduce partial x2 across the 4 k-groups of this pixel
            part += __shfl_xor(part, 16);
            part += __shfl_xor(part, 32);
            // fetch x2 for the epilogue's C rows (pixels kgrp*4 + rr)
            #pragma unroll
            for (int rr = 0; rr < 4; rr++)
                x2v[fr][img][rr] = __shfl(part, kgrp * 4 + rr);
            // bf16 hi/lo split
            short8 hi, lo;
            #pragma unroll
            for (int j = 0; j < 8; j++) {
                unsigned short hh = f2bf(xs[j]);
                hi[j] = (short)hh;
                lo[j] = (short)f2bf(xs[j] - bf2f(hh));
            }
            ah[fr][img] = hi; al[fr][img] = lo;
        }
        // store base: frag px + kgrp*4 (4-px group, never straddles a plane)
        const int prow0 = prow + kgrp * 4;
        const int b0  = prow0 / PLANE;
        const int pp0 = prow0 - b0 * PLANE;
        outbase[fr] = out + (size_t)b0 * OO * PLANE + pp0;
    }

    // ---------------- main loop: ot outer, fragment inner ----------------
    for (int ot = 0; ot < 16; ot++) {
        const int o = ot * 16 + mcol;
        const char* recg = wrecB + (size_t)o * WRECB + kgrp * 16;
        const char* recr = recg + (size_t)OO * WRECB;
        short8 bhg = *(const short8*)recg;
        short8 blg = *(const short8*)(recg + 64);
        short8 bhr = *(const short8*)recr;
        short8 blr = *(const short8*)(recr + 64);
        const float w2g = w2s[o];
        const float w2r = w2s[OO + o];

        #pragma unroll
        for (int fr = 0; fr < KSUB; fr++) {
            f32x4 cg = {0.f, 0.f, 0.f, 0.f};
            f32x4 cr = {0.f, 0.f, 0.f, 0.f};
            cg = __builtin_amdgcn_mfma_f32_16x16x32_bf16(ah[fr][0], bhg, cg, 0, 0, 0);
            cg = __builtin_amdgcn_mfma_f32_16x16x32_bf16(ah[fr][0], blg, cg, 0, 0, 0);
            cg = __builtin_amdgcn_mfma_f32_16x16x32_bf16(al[fr][0], bhg, cg, 0, 0, 0);
            cr = __builtin_amdgcn_mfma_f32_16x16x32_bf16(ah[fr][1], bhr, cr, 0, 0, 0);
            cr = __builtin_amdgcn_mfma_f32_16x16x32_bf16(ah[fr][1], blr, cr, 0, 0, 0);
            cr = __builtin_amdgcn_mfma_f32_16x16x32_bf16(al[fr][1], bhr, cr, 0, 0, 0);

            // epilogue: 4 outputs = C rows kgrp*4+rr (pixels), col o
            f32x4 res;
            #pragma unroll
            for (int rr = 0; rr < 4; rr++) {
                float d2g = fmaf(-2.f, cg[rr], x2v[fr][0][rr] + w2g);
                float d2r = fmaf(-2.f, cr[rr], x2v[fr][1][rr] + w2r);
                d2g = fmaxf(d2g, 1e-12f);
                d2r = fmaxf(d2r, 1e-12f);
                // (sqrt(d2g)+sqrt(d2r))^2 = d2g + d2r + 2*sqrt(d2g*d2r)
                float d2 = fmaf(2.f, __builtin_amdgcn_sqrtf(d2g * d2r), d2g + d2r);
                res[rr] = __expf(kneg * d2);
            }
            // 3 fr-stores per (wave, plane) hit consecutive 64B addresses
            *(f32x4*)(outbase[fr] + (size_t)o * PLANE) = res;
        }
    }
}

extern "C" void kernel_launch(void* const* d_in, const int* in_sizes, int n_in,
                              void* d_out, int out_size, void* d_ws, size_t ws_size,
                              hipStream_t stream) {
    const float* gx   = (const float*)d_in[0];
    const float* rx   = (const float*)d_in[1];
    const float* gw   = (const float*)d_in[2];
    const float* rw   = (const float*)d_in[3];
    const float* stdp = (const float*)d_in[4];
    float* out = (float*)d_out;

    dim3 grid(MTOTAL / (MTILE * KSUB), 1, 1);   // 243 blocks, exact
    dim3 block(1024, 1, 1);
    dist_rbf_mfma<<<grid, block, 0, stream>>>(gx, rx, gw, rw, stdp, out);
}